// Round 7
// baseline (231.024 us; speedup 1.0000x reference)
//
#include <hip/hip_runtime.h>

// CompositionalKoopmanOperators: B=32,N=64,ATTR=4,STATE=8,REL=4,GDIM=32,NF=128,pstep=2
// Round 7: k_edge_fused reshaped for occupancy: T=1 (2048 blocks), NO weight
// staging in LDS (B-fragments of both GEMMs read per-MFMA from L2, k_node-style).
// LDS 68.6->32 KB, grid 512->2048. Everything else unchanged from round 6.

#define ROWS 2048   // B*N
typedef unsigned short u16;
typedef unsigned int u32;
typedef __attribute__((ext_vector_type(8))) short bf16x8;   // 8 bf16 = 4 VGPR
typedef __attribute__((ext_vector_type(4))) short bf16x4;
typedef __attribute__((ext_vector_type(4))) float f32x4;

__device__ __forceinline__ float bsu(u16 u) { return __uint_as_float(((u32)u) << 16); }
__device__ __forceinline__ u16 f2b(float f) {
    u32 u = __float_as_uint(f);
    u32 r = (u + 0x7fffu + ((u >> 16) & 1u)) >> 16;   // RNE
    return (u16)r;
}

// ---------------- k_prep: one-shot bf16 weight conversions (all flat) ----------------
__global__ __launch_bounds__(256)
void k_prep(const float* __restrict__ re_w1, const float* __restrict__ rp_w,
            const float* __restrict__ oe_w1, const float* __restrict__ pp_w,
            const float* __restrict__ pr_w0, const float* __restrict__ pr_w1,
            u16* __restrict__ re_w1b, u16* __restrict__ web,
            u16* __restrict__ oe_w1b, u16* __restrict__ wrecvb, u16* __restrict__ wsendb,
            u16* __restrict__ pp_wb, u16* __restrict__ pr_w0b, u16* __restrict__ pr_w1b)
{
    int idx = blockIdx.x * 256 + threadIdx.x;
    if (idx < 16384) { re_w1b[idx] = f2b(re_w1[idx]); return; }
    idx -= 16384;
    if (idx < 16384) { int r = idx >> 7, c = idx & 127;
        web[idx] = f2b(rp_w[r * 384 + c]); return; }
    idx -= 16384;
    if (idx < 16384) { oe_w1b[idx] = f2b(oe_w1[idx]); return; }
    idx -= 16384;
    if (idx < 16384) { int r = idx >> 7, c = idx & 127;
        wrecvb[idx] = f2b(rp_w[r * 384 + 128 + c]); return; }
    idx -= 16384;
    if (idx < 16384) { int r = idx >> 7, c = idx & 127;
        wsendb[idx] = f2b(rp_w[r * 384 + 256 + c]); return; }
    idx -= 16384;
    if (idx < 32768) { pp_wb[idx] = f2b(pp_w[idx]); return; }
    idx -= 32768;
    if (idx < 16384) { pr_w0b[idx] = f2b(pr_w0[idx]); return; }
    idx -= 16384;
    if (idx < 4096)  { pr_w1b[idx] = f2b(pr_w1[idx]); }
}

// ---------------- k_node: 16 rows/block; L0 VALU + 3 MFMA GEMMs (unchanged) ----------
__global__ __launch_bounds__(256)
void k_node(const float* __restrict__ attrs, const float* __restrict__ states,
            const float* __restrict__ oe_w0, const float* __restrict__ oe_b0,
            const u16* __restrict__ oe_w1b, const float* __restrict__ oe_b1,
            const float* __restrict__ re_w0, const float* __restrict__ re_b0,
            const u16* __restrict__ wrecvb, const u16* __restrict__ wsendb,
            const float* __restrict__ rp_b,
            u16* __restrict__ objb, float* __restrict__ nr, float* __restrict__ ns,
            float* __restrict__ recvT, float* __restrict__ sendT)
{
    const int r0 = blockIdx.x * 16;
    const int t = threadIdx.x;
    __shared__ float xs[16][12];
    __shared__ float w0s[1536];
    __shared__ float rw0s[2560];
    __shared__ __align__(16) u16 hb[16 * 136];
    __shared__ __align__(16) u16 ob[16 * 136];

    if (t < 192) { int row = t / 12, c = t - row * 12;
        xs[row][c] = (c < 4) ? attrs[(r0 + row) * 4 + c] : states[(r0 + row) * 8 + (c - 4)]; }
    for (int i = t; i < 1536; i += 256) w0s[i] = oe_w0[i];
    for (int i = t; i < 2560; i += 256) rw0s[i] = re_w0[i];
    __syncthreads();

    for (int e = t; e < 2048; e += 256) {
        int row = e >> 7, o = e & 127;
        float h = oe_b0[o];
#pragma unroll
        for (int k = 0; k < 12; k++) h += w0s[o * 12 + k] * xs[row][k];
        hb[row * 136 + o] = f2b(fmaxf(h, 0.f));
        float s0 = 0.f, a0 = 0.f, a1 = 0.f;
#pragma unroll
        for (int k = 0; k < 8; k++) s0 += rw0s[o * 20 + 4 + k] * xs[row][4 + k];
#pragma unroll
        for (int k = 0; k < 4; k++) {
            a0 += rw0s[o * 20 + 12 + k] * xs[row][k];
            a1 += rw0s[o * 20 + 16 + k] * xs[row][k];
        }
        nr[(r0 + row) * 128 + o] = s0 + a0 + re_b0[o];
        ns[(r0 + row) * 128 + o] = a1 - s0;
    }
    __syncthreads();

    const int wave = t >> 6, lane = t & 63, tx = lane & 15, quad = lane >> 4;

    bf16x8 afr[4];
#pragma unroll
    for (int kk = 0; kk < 4; kk++) afr[kk] = *(const bf16x8*)&hb[tx * 136 + kk * 32 + quad * 8];
    f32x4 acc[2]; acc[0] = (f32x4){0.f,0.f,0.f,0.f}; acc[1] = acc[0];
#pragma unroll
    for (int ot = 0; ot < 2; ot++) {
        int o = (wave * 2 + ot) * 16 + tx;
#pragma unroll
        for (int kk = 0; kk < 4; kk++) {
            bf16x8 bfr = *(const bf16x8*)&oe_w1b[o * 128 + kk * 32 + quad * 8];
            acc[ot] = __builtin_amdgcn_mfma_f32_16x16x32_bf16(afr[kk], bfr, acc[ot], 0, 0, 0);
        }
    }
#pragma unroll
    for (int ot = 0; ot < 2; ot++) {
        int o = (wave * 2 + ot) * 16 + tx;
        float bia = oe_b1[o];
#pragma unroll
        for (int r = 0; r < 4; r++)
            ob[(quad * 4 + r) * 136 + o] = f2b(fmaxf(acc[ot][r] + bia, 0.f));
    }
    __syncthreads();
    { int m = t >> 4, c = t & 15;
      *(uint4*)&objb[(r0 + m) * 128 + c * 8] = *(const uint4*)&ob[m * 136 + c * 8]; }

#pragma unroll
    for (int kk = 0; kk < 4; kk++) afr[kk] = *(const bf16x8*)&ob[tx * 136 + kk * 32 + quad * 8];
    f32x4 ar[2], an[2];
    ar[0] = (f32x4){0.f,0.f,0.f,0.f}; ar[1] = ar[0]; an[0] = ar[0]; an[1] = ar[0];
#pragma unroll
    for (int ot = 0; ot < 2; ot++) {
        int o = (wave * 2 + ot) * 16 + tx;
#pragma unroll
        for (int kk = 0; kk < 4; kk++) {
            bf16x8 br = *(const bf16x8*)&wrecvb[o * 128 + kk * 32 + quad * 8];
            ar[ot] = __builtin_amdgcn_mfma_f32_16x16x32_bf16(afr[kk], br, ar[ot], 0, 0, 0);
            bf16x8 bs = *(const bf16x8*)&wsendb[o * 128 + kk * 32 + quad * 8];
            an[ot] = __builtin_amdgcn_mfma_f32_16x16x32_bf16(afr[kk], bs, an[ot], 0, 0, 0);
        }
    }
#pragma unroll
    for (int ot = 0; ot < 2; ot++) {
        int o = (wave * 2 + ot) * 16 + tx;
        float rb = rp_b[o];
#pragma unroll
        for (int r = 0; r < 4; r++) {
            recvT[(r0 + quad * 4 + r) * 128 + o] = ar[ot][r] + rb;
            sendT[(r0 + quad * 4 + r) * 128 + o] = an[ot][r];
        }
    }
}

// ---------------- k_edge_fused (T=1): h0 -> relE(LDS) -> E=W_e@relE -> step-0 LN/agg ----
__global__ __launch_bounds__(256)
void k_edge_fused(const float* __restrict__ rel_attrs,
                  const float* __restrict__ re_w0, const u16* __restrict__ re_w1b,
                  const u16* __restrict__ web, const float* __restrict__ re_b1,
                  const float* __restrict__ rp_lnw, const float* __restrict__ rp_lnb,
                  const float* __restrict__ nr, const float* __restrict__ ns,
                  const float* __restrict__ recvT, const float* __restrict__ sendT,
                  u16* __restrict__ Ebuf, u16* __restrict__ aggb)
{
    const int blkg = blockIdx.x;    // b*64 + i
    const int b = blkg >> 6;
    const int t = threadIdx.x;
    __shared__ __align__(16) u16 hsb[64 * 144];     // h0 / relE tile (18432 B)
    __shared__ float nrs[128];
    __shared__ float w0a[128][4];
    __shared__ float ras[64][4];
    __shared__ float scr[16 * 132];
    __shared__ float lnws[128], lnbs[128];

    if (t < 128) {
        lnws[t] = rp_lnw[t]; lnbs[t] = rp_lnb[t];
        nrs[t] = nr[blkg * 128 + t];
#pragma unroll
        for (int c = 0; c < 4; c++) w0a[t][c] = re_w0[t * 20 + c];
    } else if (t < 192) {
        int j = t - 128;
#pragma unroll
        for (int c = 0; c < 4; c++) ras[j][c] = rel_attrs[(blkg * 64 + j) * 4 + c];
    }
    __syncthreads();

    const int wave = t >> 6, lane = t & 63, tx = lane & 15, quad = lane >> 4;

    // phase 1: h0[j][o]
    for (int e = t; e < 64 * 128; e += 256) {
        int j = e >> 7, o = e & 127;
        float v = nrs[o] + ns[(b * 64 + j) * 128 + o];
#pragma unroll
        for (int c = 0; c < 4; c++) v += w0a[o][c] * ras[j][c];
        hsb[j * 144 + o] = f2b(fmaxf(v, 0.f));
    }
    __syncthreads();

    // GEMM1: relE[j][o] = relu(sum_k h0[j][k] * re_w1[o][k] + b)   (B from L2)
    bf16x8 afr[4];
#pragma unroll
    for (int kk = 0; kk < 4; kk++)
        afr[kk] = *(const bf16x8*)&hsb[(wave * 16 + tx) * 144 + kk * 32 + quad * 8];
    f32x4 acc[8];
#pragma unroll
    for (int oo = 0; oo < 8; oo++) acc[oo] = (f32x4){0.f, 0.f, 0.f, 0.f};
#pragma unroll
    for (int oo = 0; oo < 8; oo++) {
        const int o = oo * 16 + tx;
#pragma unroll
        for (int kk = 0; kk < 4; kk++) {
            bf16x8 bfr = *(const bf16x8*)&re_w1b[o * 128 + kk * 32 + quad * 8];
            acc[oo] = __builtin_amdgcn_mfma_f32_16x16x32_bf16(afr[kk], bfr, acc[oo], 0, 0, 0);
        }
    }
    // epilogue1 -> relE into own wave's 16-row band (bands are wave-private)
#pragma unroll
    for (int oo = 0; oo < 8; oo++) {
        const int o = oo * 16 + tx;
        float bia = re_b1[o];
#pragma unroll
        for (int r = 0; r < 4; r++)
            hsb[(wave * 16 + quad * 4 + r) * 144 + o] = f2b(fmaxf(acc[oo][r] + bia, 0.f));
    }
    // GEMM2: E[j][o2] = sum_o relE[j][o] * W_e[o2][o]   (A own band, B from L2)
    bf16x8 af2[4];
#pragma unroll
    for (int kk = 0; kk < 4; kk++)
        af2[kk] = *(const bf16x8*)&hsb[(wave * 16 + tx) * 144 + kk * 32 + quad * 8];
    f32x4 acc2[8];
#pragma unroll
    for (int oo = 0; oo < 8; oo++) acc2[oo] = (f32x4){0.f, 0.f, 0.f, 0.f};
#pragma unroll
    for (int oo = 0; oo < 8; oo++) {
        const int o2 = oo * 16 + tx;
#pragma unroll
        for (int kk = 0; kk < 4; kk++) {
            bf16x8 bfr = *(const bf16x8*)&web[o2 * 128 + kk * 32 + quad * 8];
            acc2[oo] = __builtin_amdgcn_mfma_f32_16x16x32_bf16(af2[kk], bfr, acc2[oo], 0, 0, 0);
        }
    }
    // store E in C-fragment order: ((tid*8+oo)*64+lane)*4, tid = blkg*4+wave
    const int tid = blkg * 4 + wave;
#pragma unroll
    for (int oo = 0; oo < 8; oo++) {
        bf16x4 v;
        v[0] = (short)f2b(acc2[oo][0]); v[1] = (short)f2b(acc2[oo][1]);
        v[2] = (short)f2b(acc2[oo][2]); v[3] = (short)f2b(acc2[oo][3]);
        *(bf16x4*)(Ebuf + ((size_t)(tid * 8 + oo) * 64 + lane) * 4) = v;
    }

    // step-0: y = E + recvT0[i] + sendT0[j]; LN; relu; agg
    const int jrow = wave * 16 + quad * 4;
#pragma unroll
    for (int oo = 0; oo < 8; oo++) {
        const int o = oo * 16 + tx;
        float rv = recvT[blkg * 128 + o];
#pragma unroll
        for (int r = 0; r < 4; r++)
            acc2[oo][r] += rv + sendT[(b * 64 + jrow + r) * 128 + o];
    }
    float s[4], q[4];
#pragma unroll
    for (int r = 0; r < 4; r++) {
        s[r] = 0.f; q[r] = 0.f;
#pragma unroll
        for (int oo = 0; oo < 8; oo++) { s[r] += acc2[oo][r]; q[r] += acc2[oo][r] * acc2[oo][r]; }
    }
#pragma unroll
    for (int m = 1; m < 16; m <<= 1) {
#pragma unroll
        for (int r = 0; r < 4; r++) {
            s[r] += __shfl_xor(s[r], m, 64);
            q[r] += __shfl_xor(q[r], m, 64);
        }
    }
    float mu[4], rs[4];
#pragma unroll
    for (int r = 0; r < 4; r++) {
        mu[r] = s[r] * (1.f / 128.f);
        float var = q[r] * (1.f / 128.f) - mu[r] * mu[r];
        rs[r] = rsqrtf(var + 1e-5f);
    }
    float pa[8];
#pragma unroll
    for (int oo = 0; oo < 8; oo++) {
        const int o = oo * 16 + tx;
        float lw = lnws[o], lb = lnbs[o];
        float p = 0.f;
#pragma unroll
        for (int r = 0; r < 4; r++) {
            float z = (acc2[oo][r] - mu[r]) * rs[r] * lw + lb;
            p += fmaxf(z, 0.f);
        }
        pa[oo] = p;
    }
    const int grp = wave * 4 + quad;
#pragma unroll
    for (int oo = 0; oo < 8; oo++) scr[grp * 132 + oo * 16 + tx] = pa[oo];
    __syncthreads();
    if (t < 128) {
        float sum = 0.f;
#pragma unroll
        for (int gg = 0; gg < 16; gg++) sum += scr[gg * 132 + t];
        aggb[blkg * 128 + t] = f2b(sum);
    }
}

// ---------------- k_prop_edge2: step-1, no GEMM (E + recv/send -> LN -> relu -> agg) ----
__global__ __launch_bounds__(256)
void k_prop_edge2(const u16* __restrict__ Ebuf,
                  const float* __restrict__ rp_lnw, const float* __restrict__ rp_lnb,
                  const float* __restrict__ recvT, const float* __restrict__ sendT,
                  u16* __restrict__ aggb)
{
    const int blk = blockIdx.x;   // b*64 + i
    const int b = blk >> 6;
    const int t = threadIdx.x;
    __shared__ float scr[16 * 132];
    __shared__ float lnws[128], lnbs[128];
    if (t < 128) { lnws[t] = rp_lnw[t]; lnbs[t] = rp_lnb[t]; }
    __syncthreads();

    const int wave = t >> 6, lane = t & 63, tx = lane & 15, quad = lane >> 4;
    const int tid = blk * 4 + wave;
    const int jrow = wave * 16 + quad * 4;

    float y[8][4];
#pragma unroll
    for (int oo = 0; oo < 8; oo++) {
        bf16x4 v = *(const bf16x4*)(Ebuf + ((size_t)(tid * 8 + oo) * 64 + lane) * 4);
        const int o = oo * 16 + tx;
        float rv = recvT[blk * 128 + o];
#pragma unroll
        for (int r = 0; r < 4; r++)
            y[oo][r] = bsu((u16)v[r]) + rv + sendT[(b * 64 + jrow + r) * 128 + o];
    }
    float s[4], q[4];
#pragma unroll
    for (int r = 0; r < 4; r++) {
        s[r] = 0.f; q[r] = 0.f;
#pragma unroll
        for (int oo = 0; oo < 8; oo++) { s[r] += y[oo][r]; q[r] += y[oo][r] * y[oo][r]; }
    }
#pragma unroll
    for (int m = 1; m < 16; m <<= 1) {
#pragma unroll
        for (int r = 0; r < 4; r++) {
            s[r] += __shfl_xor(s[r], m, 64);
            q[r] += __shfl_xor(q[r], m, 64);
        }
    }
    float mu[4], rs[4];
#pragma unroll
    for (int r = 0; r < 4; r++) {
        mu[r] = s[r] * (1.f / 128.f);
        rs[r] = rsqrtf(q[r] * (1.f / 128.f) - mu[r] * mu[r] + 1e-5f);
    }
    float pa[8];
#pragma unroll
    for (int oo = 0; oo < 8; oo++) {
        const int o = oo * 16 + tx;
        float lw = lnws[o], lb = lnbs[o];
        float p = 0.f;
#pragma unroll
        for (int r = 0; r < 4; r++) {
            float z = (y[oo][r] - mu[r]) * rs[r] * lw + lb;
            p += fmaxf(z, 0.f);
        }
        pa[oo] = p;
    }
    const int grp = wave * 4 + quad;
#pragma unroll
    for (int oo = 0; oo < 8; oo++) scr[grp * 132 + oo * 16 + tx] = pa[oo];
    __syncthreads();
    if (t < 128) {
        float sum = 0.f;
#pragma unroll
        for (int gg = 0; gg < 16; gg++) sum += scr[gg * 132 + t];
        aggb[blk * 128 + t] = f2b(sum);
    }
}

// ---------------- k_prop_node: 16 rows/block MFMA (unchanged) ----------------
__global__ __launch_bounds__(256)
void k_prop_node(const u16* __restrict__ aggb,
                 const u16* __restrict__ pp_wb, const float* __restrict__ pp_b,
                 const float* __restrict__ pp_lnw, const float* __restrict__ pp_lnb,
                 const u16* __restrict__ wrecvb, const u16* __restrict__ wsendb,
                 const float* __restrict__ rp_b,
                 u16* __restrict__ objb, float* __restrict__ recvT, float* __restrict__ sendT,
                 int compute_terms)
{
    const int r0 = blockIdx.x * 16;
    const int t = threadIdx.x;
    __shared__ __align__(16) u16 ab[16 * 264];
    __shared__ __align__(16) u16 ob[16 * 136];
    __shared__ float redS[64], redQ[64];

    for (int i = t; i < 512; i += 256) {
        int m = i >> 5, c = i & 31;
        uint4 v = (c < 16) ? *(const uint4*)&objb[(r0 + m) * 128 + (c & 15) * 8]
                           : *(const uint4*)&aggb[(r0 + m) * 128 + (c - 16) * 8];
        *(uint4*)&ab[m * 264 + c * 8] = v;
    }
    __syncthreads();

    const int wave = t >> 6, lane = t & 63, tx = lane & 15, quad = lane >> 4;
    bf16x8 afr[8];
#pragma unroll
    for (int kk = 0; kk < 8; kk++) afr[kk] = *(const bf16x8*)&ab[tx * 264 + kk * 32 + quad * 8];
    f32x4 acc[2]; acc[0] = (f32x4){0.f,0.f,0.f,0.f}; acc[1] = acc[0];
#pragma unroll
    for (int ot = 0; ot < 2; ot++) {
        int o = (wave * 2 + ot) * 16 + tx;
#pragma unroll
        for (int kk = 0; kk < 8; kk++) {
            bf16x8 bfr = *(const bf16x8*)&pp_wb[o * 256 + kk * 32 + quad * 8];
            acc[ot] = __builtin_amdgcn_mfma_f32_16x16x32_bf16(afr[kk], bfr, acc[ot], 0, 0, 0);
        }
    }
#pragma unroll
    for (int ot = 0; ot < 2; ot++) {
        float bia = pp_b[(wave * 2 + ot) * 16 + tx];
#pragma unroll
        for (int r = 0; r < 4; r++) acc[ot][r] += bia;
    }

    float s[4], q[4];
#pragma unroll
    for (int r = 0; r < 4; r++) {
        s[r] = acc[0][r] + acc[1][r];
        q[r] = acc[0][r] * acc[0][r] + acc[1][r] * acc[1][r];
    }
#pragma unroll
    for (int m = 1; m < 16; m <<= 1) {
#pragma unroll
        for (int r = 0; r < 4; r++) {
            s[r] += __shfl_xor(s[r], m, 64);
            q[r] += __shfl_xor(q[r], m, 64);
        }
    }
    if (tx == 0) {
#pragma unroll
        for (int r = 0; r < 4; r++) {
            redS[wave * 16 + quad * 4 + r] = s[r];
            redQ[wave * 16 + quad * 4 + r] = q[r];
        }
    }
    __syncthreads();
    float mu[4], rs[4];
#pragma unroll
    for (int r = 0; r < 4; r++) {
        int m = quad * 4 + r;
        float ss = redS[m] + redS[16 + m] + redS[32 + m] + redS[48 + m];
        float qq = redQ[m] + redQ[16 + m] + redQ[32 + m] + redQ[48 + m];
        mu[r] = ss * (1.f / 128.f);
        rs[r] = rsqrtf(qq * (1.f / 128.f) - mu[r] * mu[r] + 1e-5f);
    }
#pragma unroll
    for (int ot = 0; ot < 2; ot++) {
        int o = (wave * 2 + ot) * 16 + tx;
        float lw = pp_lnw[o], lb = pp_lnb[o];
#pragma unroll
        for (int r = 0; r < 4; r++) {
            float z = (acc[ot][r] - mu[r]) * rs[r] * lw + lb;
            ob[(quad * 4 + r) * 136 + o] = f2b(fmaxf(z, 0.f));
        }
    }
    __syncthreads();
    { int m = t >> 4, c = t & 15;
      *(uint4*)&objb[(r0 + m) * 128 + c * 8] = *(const uint4*)&ob[m * 136 + c * 8]; }

    if (compute_terms) {
        bf16x8 af2[4];
#pragma unroll
        for (int kk = 0; kk < 4; kk++) af2[kk] = *(const bf16x8*)&ob[tx * 136 + kk * 32 + quad * 8];
        f32x4 ar[2], an[2];
        ar[0] = (f32x4){0.f,0.f,0.f,0.f}; ar[1] = ar[0]; an[0] = ar[0]; an[1] = ar[0];
#pragma unroll
        for (int ot = 0; ot < 2; ot++) {
            int o = (wave * 2 + ot) * 16 + tx;
#pragma unroll
            for (int kk = 0; kk < 4; kk++) {
                bf16x8 br = *(const bf16x8*)&wrecvb[o * 128 + kk * 32 + quad * 8];
                ar[ot] = __builtin_amdgcn_mfma_f32_16x16x32_bf16(af2[kk], br, ar[ot], 0, 0, 0);
                bf16x8 bs = *(const bf16x8*)&wsendb[o * 128 + kk * 32 + quad * 8];
                an[ot] = __builtin_amdgcn_mfma_f32_16x16x32_bf16(af2[kk], bs, an[ot], 0, 0, 0);
            }
        }
#pragma unroll
        for (int ot = 0; ot < 2; ot++) {
            int o = (wave * 2 + ot) * 16 + tx;
            float rb = rp_b[o];
#pragma unroll
            for (int r = 0; r < 4; r++) {
                recvT[(r0 + quad * 4 + r) * 128 + o] = ar[ot][r] + rb;
                sendT[(r0 + quad * 4 + r) * 128 + o] = an[ot][r];
            }
        }
    }
}

// ---------------- k_predict: 16 rows/block MFMA (unchanged) ----------------
__global__ __launch_bounds__(256)
void k_predict(const u16* __restrict__ objb,
               const u16* __restrict__ pr_w0b, const float* __restrict__ pr_b0,
               const u16* __restrict__ pr_w1b, const float* __restrict__ pr_b1,
               float* __restrict__ out)
{
    const int r0 = blockIdx.x * 16;
    const int t = threadIdx.x;
    __shared__ __align__(16) u16 ab[16 * 136];
    __shared__ __align__(16) u16 hb2[16 * 136];
    { int m = t >> 4, c = t & 15;
      *(uint4*)&ab[m * 136 + c * 8] = *(const uint4*)&objb[(r0 + m) * 128 + c * 8]; }
    __syncthreads();

    const int wave = t >> 6, lane = t & 63, tx = lane & 15, quad = lane >> 4;
    bf16x8 afr[4];
#pragma unroll
    for (int kk = 0; kk < 4; kk++) afr[kk] = *(const bf16x8*)&ab[tx * 136 + kk * 32 + quad * 8];
    f32x4 acc[2]; acc[0] = (f32x4){0.f,0.f,0.f,0.f}; acc[1] = acc[0];
#pragma unroll
    for (int ot = 0; ot < 2; ot++) {
        int o = (wave * 2 + ot) * 16 + tx;
#pragma unroll
        for (int kk = 0; kk < 4; kk++) {
            bf16x8 bfr = *(const bf16x8*)&pr_w0b[o * 128 + kk * 32 + quad * 8];
            acc[ot] = __builtin_amdgcn_mfma_f32_16x16x32_bf16(afr[kk], bfr, acc[ot], 0, 0, 0);
        }
    }
#pragma unroll
    for (int ot = 0; ot < 2; ot++) {
        int o = (wave * 2 + ot) * 16 + tx;
        float bia = pr_b0[o];
#pragma unroll
        for (int r = 0; r < 4; r++)
            hb2[(quad * 4 + r) * 136 + o] = f2b(fmaxf(acc[ot][r] + bia, 0.f));
    }
    __syncthreads();
    if (wave < 2) {
        bf16x8 af2[4];
#pragma unroll
        for (int kk = 0; kk < 4; kk++) af2[kk] = *(const bf16x8*)&hb2[tx * 136 + kk * 32 + quad * 8];
        f32x4 a2 = (f32x4){0.f,0.f,0.f,0.f};
        int o = wave * 16 + tx;
#pragma unroll
        for (int kk = 0; kk < 4; kk++) {
            bf16x8 bfr = *(const bf16x8*)&pr_w1b[o * 128 + kk * 32 + quad * 8];
            a2 = __builtin_amdgcn_mfma_f32_16x16x32_bf16(af2[kk], bfr, a2, 0, 0, 0);
        }
        float bia = pr_b1[o];
#pragma unroll
        for (int r = 0; r < 4; r++)
            out[(r0 + quad * 4 + r) * 32 + o] = tanhf(a2[r] + bia);
    }
}

extern "C" void kernel_launch(void* const* d_in, const int* in_sizes, int n_in,
                              void* d_out, int out_size, void* d_ws, size_t ws_size,
                              hipStream_t stream)
{
    const float* attrs    = (const float*)d_in[0];
    const float* states   = (const float*)d_in[1];
    const float* rel_attrs= (const float*)d_in[3];
    const float* oe_w0 = (const float*)d_in[4];
    const float* oe_b0 = (const float*)d_in[5];
    const float* oe_w1 = (const float*)d_in[6];
    const float* oe_b1 = (const float*)d_in[7];
    const float* re_w0 = (const float*)d_in[8];
    const float* re_b0 = (const float*)d_in[9];
    const float* re_w1 = (const float*)d_in[10];
    const float* re_b1 = (const float*)d_in[11];
    const float* rp_w  = (const float*)d_in[12];
    const float* rp_b  = (const float*)d_in[13];
    const float* rp_lnw= (const float*)d_in[14];
    const float* rp_lnb= (const float*)d_in[15];
    const float* pp_w  = (const float*)d_in[16];
    const float* pp_b  = (const float*)d_in[17];
    const float* pp_lnw= (const float*)d_in[18];
    const float* pp_lnb= (const float*)d_in[19];
    const float* pr_w0 = (const float*)d_in[20];
    const float* pr_b0 = (const float*)d_in[21];
    const float* pr_w1 = (const float*)d_in[22];
    const float* pr_b1 = (const float*)d_in[23];
    // d_in[24] = pstep (always 2)

    float* ws    = (float*)d_ws;
    float* nr    = ws;
    float* ns    = nr    + ROWS * 128;
    float* recvT = ns    + ROWS * 128;
    float* sendT = recvT + ROWS * 128;
    u16* re_w1b = (u16*)(sendT + ROWS * 128);
    u16* web    = re_w1b + 16384;
    u16* oe_w1b = web    + 16384;
    u16* wrecvb = oe_w1b + 16384;
    u16* wsendb = wrecvb + 16384;
    u16* pp_wb  = wsendb + 16384;
    u16* pr_w0b = pp_wb  + 32768;
    u16* pr_w1b = pr_w0b + 16384;
    u16* objb   = pr_w1b + 4096;
    u16* aggb   = objb + ROWS * 128;
    u16* Ebuf   = aggb + ROWS * 128;   // 8192 tiles * 8 * 64 * 4 bf16 (33.5 MB)

    k_prep<<<528, 256, 0, stream>>>(re_w1, rp_w, oe_w1, pp_w, pr_w0, pr_w1,
                                    re_w1b, web, oe_w1b, wrecvb, wsendb,
                                    pp_wb, pr_w0b, pr_w1b);
    k_node<<<128, 256, 0, stream>>>(attrs, states, oe_w0, oe_b0, oe_w1b, oe_b1,
                                    re_w0, re_b0, wrecvb, wsendb, rp_b,
                                    objb, nr, ns, recvT, sendT);
    k_edge_fused<<<2048, 256, 0, stream>>>(rel_attrs, re_w0, re_w1b, web, re_b1,
                                           rp_lnw, rp_lnb, nr, ns, recvT, sendT,
                                           Ebuf, aggb);
    k_prop_node<<<128, 256, 0, stream>>>(aggb, pp_wb, pp_b, pp_lnw, pp_lnb,
                                         wrecvb, wsendb, rp_b,
                                         objb, recvT, sendT, 1);
    k_prop_edge2<<<2048, 256, 0, stream>>>(Ebuf, rp_lnw, rp_lnb, recvT, sendT, aggb);
    k_prop_node<<<128, 256, 0, stream>>>(aggb, pp_wb, pp_b, pp_lnw, pp_lnb,
                                         wrecvb, wsendb, rp_b,
                                         objb, recvT, sendT, 0);
    k_predict<<<128, 256, 0, stream>>>(objb, pr_w0b, pr_b0, pr_w1b, pr_b1, (float*)d_out);
}

// Round 8
// 187.434 us; speedup vs baseline: 1.2326x; 1.2326x over previous
//
#include <hip/hip_runtime.h>

// CompositionalKoopmanOperators: B=32,N=64,ATTR=4,STATE=8,REL=4,GDIM=32,NF=128,pstep=2
// Round 8: k_edge_fused restructured so each wave owns a 32-col output slice for
// all 64 rows: B-fragments (8/GEMM/wave = 32 VGPR) loaded ONCE per block from L2
// and held in registers across all MFMAs. A-frags from LDS (broadcast across
// waves). No weight staging in LDS (~26 KB total). r7's failure mode (per-MFMA
// B reads from L2: 200 B/cyc/CU needed vs 56 available) is eliminated.

#define ROWS 2048   // B*N
typedef unsigned short u16;
typedef unsigned int u32;
typedef __attribute__((ext_vector_type(8))) short bf16x8;   // 8 bf16 = 4 VGPR
typedef __attribute__((ext_vector_type(4))) short bf16x4;
typedef __attribute__((ext_vector_type(4))) float f32x4;

__device__ __forceinline__ float bsu(u16 u) { return __uint_as_float(((u32)u) << 16); }
__device__ __forceinline__ u16 f2b(float f) {
    u32 u = __float_as_uint(f);
    u32 r = (u + 0x7fffu + ((u >> 16) & 1u)) >> 16;   // RNE
    return (u16)r;
}

// ---------------- k_prep: one-shot bf16 weight conversions (all flat) ----------------
__global__ __launch_bounds__(256)
void k_prep(const float* __restrict__ re_w1, const float* __restrict__ rp_w,
            const float* __restrict__ oe_w1, const float* __restrict__ pp_w,
            const float* __restrict__ pr_w0, const float* __restrict__ pr_w1,
            u16* __restrict__ re_w1b, u16* __restrict__ web,
            u16* __restrict__ oe_w1b, u16* __restrict__ wrecvb, u16* __restrict__ wsendb,
            u16* __restrict__ pp_wb, u16* __restrict__ pr_w0b, u16* __restrict__ pr_w1b)
{
    int idx = blockIdx.x * 256 + threadIdx.x;
    if (idx < 16384) { re_w1b[idx] = f2b(re_w1[idx]); return; }
    idx -= 16384;
    if (idx < 16384) { int r = idx >> 7, c = idx & 127;
        web[idx] = f2b(rp_w[r * 384 + c]); return; }
    idx -= 16384;
    if (idx < 16384) { oe_w1b[idx] = f2b(oe_w1[idx]); return; }
    idx -= 16384;
    if (idx < 16384) { int r = idx >> 7, c = idx & 127;
        wrecvb[idx] = f2b(rp_w[r * 384 + 128 + c]); return; }
    idx -= 16384;
    if (idx < 16384) { int r = idx >> 7, c = idx & 127;
        wsendb[idx] = f2b(rp_w[r * 384 + 256 + c]); return; }
    idx -= 16384;
    if (idx < 32768) { pp_wb[idx] = f2b(pp_w[idx]); return; }
    idx -= 32768;
    if (idx < 16384) { pr_w0b[idx] = f2b(pr_w0[idx]); return; }
    idx -= 16384;
    if (idx < 4096)  { pr_w1b[idx] = f2b(pr_w1[idx]); }
}

// ---------------- k_node: 16 rows/block; L0 VALU + 3 MFMA GEMMs (unchanged) ----------
__global__ __launch_bounds__(256)
void k_node(const float* __restrict__ attrs, const float* __restrict__ states,
            const float* __restrict__ oe_w0, const float* __restrict__ oe_b0,
            const u16* __restrict__ oe_w1b, const float* __restrict__ oe_b1,
            const float* __restrict__ re_w0, const float* __restrict__ re_b0,
            const u16* __restrict__ wrecvb, const u16* __restrict__ wsendb,
            const float* __restrict__ rp_b,
            u16* __restrict__ objb, float* __restrict__ nr, float* __restrict__ ns,
            float* __restrict__ recvT, float* __restrict__ sendT)
{
    const int r0 = blockIdx.x * 16;
    const int t = threadIdx.x;
    __shared__ float xs[16][12];
    __shared__ float w0s[1536];
    __shared__ float rw0s[2560];
    __shared__ __align__(16) u16 hb[16 * 136];
    __shared__ __align__(16) u16 ob[16 * 136];

    if (t < 192) { int row = t / 12, c = t - row * 12;
        xs[row][c] = (c < 4) ? attrs[(r0 + row) * 4 + c] : states[(r0 + row) * 8 + (c - 4)]; }
    for (int i = t; i < 1536; i += 256) w0s[i] = oe_w0[i];
    for (int i = t; i < 2560; i += 256) rw0s[i] = re_w0[i];
    __syncthreads();

    for (int e = t; e < 2048; e += 256) {
        int row = e >> 7, o = e & 127;
        float h = oe_b0[o];
#pragma unroll
        for (int k = 0; k < 12; k++) h += w0s[o * 12 + k] * xs[row][k];
        hb[row * 136 + o] = f2b(fmaxf(h, 0.f));
        float s0 = 0.f, a0 = 0.f, a1 = 0.f;
#pragma unroll
        for (int k = 0; k < 8; k++) s0 += rw0s[o * 20 + 4 + k] * xs[row][4 + k];
#pragma unroll
        for (int k = 0; k < 4; k++) {
            a0 += rw0s[o * 20 + 12 + k] * xs[row][k];
            a1 += rw0s[o * 20 + 16 + k] * xs[row][k];
        }
        nr[(r0 + row) * 128 + o] = s0 + a0 + re_b0[o];
        ns[(r0 + row) * 128 + o] = a1 - s0;
    }
    __syncthreads();

    const int wave = t >> 6, lane = t & 63, tx = lane & 15, quad = lane >> 4;

    bf16x8 afr[4];
#pragma unroll
    for (int kk = 0; kk < 4; kk++) afr[kk] = *(const bf16x8*)&hb[tx * 136 + kk * 32 + quad * 8];
    f32x4 acc[2]; acc[0] = (f32x4){0.f,0.f,0.f,0.f}; acc[1] = acc[0];
#pragma unroll
    for (int ot = 0; ot < 2; ot++) {
        int o = (wave * 2 + ot) * 16 + tx;
#pragma unroll
        for (int kk = 0; kk < 4; kk++) {
            bf16x8 bfr = *(const bf16x8*)&oe_w1b[o * 128 + kk * 32 + quad * 8];
            acc[ot] = __builtin_amdgcn_mfma_f32_16x16x32_bf16(afr[kk], bfr, acc[ot], 0, 0, 0);
        }
    }
#pragma unroll
    for (int ot = 0; ot < 2; ot++) {
        int o = (wave * 2 + ot) * 16 + tx;
        float bia = oe_b1[o];
#pragma unroll
        for (int r = 0; r < 4; r++)
            ob[(quad * 4 + r) * 136 + o] = f2b(fmaxf(acc[ot][r] + bia, 0.f));
    }
    __syncthreads();
    { int m = t >> 4, c = t & 15;
      *(uint4*)&objb[(r0 + m) * 128 + c * 8] = *(const uint4*)&ob[m * 136 + c * 8]; }

#pragma unroll
    for (int kk = 0; kk < 4; kk++) afr[kk] = *(const bf16x8*)&ob[tx * 136 + kk * 32 + quad * 8];
    f32x4 ar[2], an[2];
    ar[0] = (f32x4){0.f,0.f,0.f,0.f}; ar[1] = ar[0]; an[0] = ar[0]; an[1] = ar[0];
#pragma unroll
    for (int ot = 0; ot < 2; ot++) {
        int o = (wave * 2 + ot) * 16 + tx;
#pragma unroll
        for (int kk = 0; kk < 4; kk++) {
            bf16x8 br = *(const bf16x8*)&wrecvb[o * 128 + kk * 32 + quad * 8];
            ar[ot] = __builtin_amdgcn_mfma_f32_16x16x32_bf16(afr[kk], br, ar[ot], 0, 0, 0);
            bf16x8 bs = *(const bf16x8*)&wsendb[o * 128 + kk * 32 + quad * 8];
            an[ot] = __builtin_amdgcn_mfma_f32_16x16x32_bf16(afr[kk], bs, an[ot], 0, 0, 0);
        }
    }
#pragma unroll
    for (int ot = 0; ot < 2; ot++) {
        int o = (wave * 2 + ot) * 16 + tx;
        float rb = rp_b[o];
#pragma unroll
        for (int r = 0; r < 4; r++) {
            recvT[(r0 + quad * 4 + r) * 128 + o] = ar[ot][r] + rb;
            sendT[(r0 + quad * 4 + r) * 128 + o] = an[ot][r];
        }
    }
}

// ---------------- k_edge_fused (r8): wave = 32-col slice, B in registers ----------------
__global__ __launch_bounds__(256)
void k_edge_fused(const float* __restrict__ rel_attrs,
                  const float* __restrict__ re_w0, const u16* __restrict__ re_w1b,
                  const u16* __restrict__ web, const float* __restrict__ re_b1,
                  const float* __restrict__ rp_lnw, const float* __restrict__ rp_lnb,
                  const float* __restrict__ nr, const float* __restrict__ ns,
                  const float* __restrict__ recvT, const float* __restrict__ sendT,
                  u16* __restrict__ Ebuf, u16* __restrict__ aggb)
{
    const int blkg = blockIdx.x;    // b*64 + i
    const int b = blkg >> 6;
    const int t = threadIdx.x;
    __shared__ __align__(16) u16 hsb[64 * 144];     // h0, then relE (18432 B)
    __shared__ float nrs[128];
    __shared__ float w0a[128][4];
    __shared__ float ras[64][4];
    __shared__ float lnws[128], lnbs[128];
    __shared__ float redS[256], redQ[256];          // [wave][row]

    if (t < 128) {
        lnws[t] = rp_lnw[t]; lnbs[t] = rp_lnb[t];
        nrs[t] = nr[blkg * 128 + t];
#pragma unroll
        for (int c = 0; c < 4; c++) w0a[t][c] = re_w0[t * 20 + c];
    } else if (t < 192) {
        int j = t - 128;
#pragma unroll
        for (int c = 0; c < 4; c++) ras[j][c] = rel_attrs[(blkg * 64 + j) * 4 + c];
    }
    __syncthreads();

    const int w = t >> 6, lane = t & 63, tx = lane & 15, quad = lane >> 4;
    const int ob = w * 32;              // this wave's output-column base

    // phase 1: h0[j][o]
    for (int e = t; e < 64 * 128; e += 256) {
        int j = e >> 7, o = e & 127;
        float v = nrs[o] + ns[(b * 64 + j) * 128 + o];
#pragma unroll
        for (int c = 0; c < 4; c++) v += w0a[o][c] * ras[j][c];
        hsb[j * 144 + o] = f2b(fmaxf(v, 0.f));
    }

    // B1 fragments: held in registers for the whole GEMM (32 VGPR)
    bf16x8 b1[2][4];
#pragma unroll
    for (int ot = 0; ot < 2; ot++)
#pragma unroll
        for (int kk = 0; kk < 4; kk++)
            b1[ot][kk] = *(const bf16x8*)&re_w1b[(ob + ot * 16 + tx) * 128 + kk * 32 + quad * 8];
    __syncthreads();

    // GEMM1: relE[j][o] over all 64 j, o in [ob, ob+32)
    f32x4 acc[4][2];
#pragma unroll
    for (int jt = 0; jt < 4; jt++) { acc[jt][0] = (f32x4){0.f,0.f,0.f,0.f}; acc[jt][1] = acc[jt][0]; }
#pragma unroll
    for (int jt = 0; jt < 4; jt++) {
        bf16x8 afr[4];
#pragma unroll
        for (int kk = 0; kk < 4; kk++)
            afr[kk] = *(const bf16x8*)&hsb[(jt * 16 + tx) * 144 + kk * 32 + quad * 8];
#pragma unroll
        for (int ot = 0; ot < 2; ot++)
#pragma unroll
            for (int kk = 0; kk < 4; kk++)
                acc[jt][ot] = __builtin_amdgcn_mfma_f32_16x16x32_bf16(afr[kk], b1[ot][kk], acc[jt][ot], 0, 0, 0);
    }
    __syncthreads();

    // epilogue1: relu(acc + bias) -> relE back into hsb
    {
        float bia0 = re_b1[ob + tx], bia1 = re_b1[ob + 16 + tx];
#pragma unroll
        for (int jt = 0; jt < 4; jt++)
#pragma unroll
            for (int r = 0; r < 4; r++) {
                int j = jt * 16 + quad * 4 + r;
                hsb[j * 144 + ob + tx]      = f2b(fmaxf(acc[jt][0][r] + bia0, 0.f));
                hsb[j * 144 + ob + 16 + tx] = f2b(fmaxf(acc[jt][1][r] + bia1, 0.f));
            }
    }
    // B2 fragments (reuse register pressure window after GEMM1)
    bf16x8 b2[2][4];
#pragma unroll
    for (int ot = 0; ot < 2; ot++)
#pragma unroll
        for (int kk = 0; kk < 4; kk++)
            b2[ot][kk] = *(const bf16x8*)&web[(ob + ot * 16 + tx) * 128 + kk * 32 + quad * 8];
    __syncthreads();

    // GEMM2: E[j][o2] = sum_o relE[j][o] * W_e[o2][o]
    f32x4 acc2[4][2];
#pragma unroll
    for (int jt = 0; jt < 4; jt++) { acc2[jt][0] = (f32x4){0.f,0.f,0.f,0.f}; acc2[jt][1] = acc2[jt][0]; }
#pragma unroll
    for (int jt = 0; jt < 4; jt++) {
        bf16x8 afr[4];
#pragma unroll
        for (int kk = 0; kk < 4; kk++)
            afr[kk] = *(const bf16x8*)&hsb[(jt * 16 + tx) * 144 + kk * 32 + quad * 8];
#pragma unroll
        for (int ot = 0; ot < 2; ot++)
#pragma unroll
            for (int kk = 0; kk < 4; kk++)
                acc2[jt][ot] = __builtin_amdgcn_mfma_f32_16x16x32_bf16(afr[kk], b2[ot][kk], acc2[jt][ot], 0, 0, 0);
    }

    // store E (pre recv/send) in prop_edge2-compatible fragment order
#pragma unroll
    for (int jt = 0; jt < 4; jt++)
#pragma unroll
        for (int ot = 0; ot < 2; ot++) {
            bf16x4 v;
            v[0] = (short)f2b(acc2[jt][ot][0]); v[1] = (short)f2b(acc2[jt][ot][1]);
            v[2] = (short)f2b(acc2[jt][ot][2]); v[3] = (short)f2b(acc2[jt][ot][3]);
            *(bf16x4*)(Ebuf + ((size_t)((blkg * 4 + jt) * 8 + (2 * w + ot)) * 64 + lane) * 4) = v;
        }

    // y = E + recvT[i][o] + sendT[j][o]
    {
        float rv0 = recvT[blkg * 128 + ob + tx];
        float rv1 = recvT[blkg * 128 + ob + 16 + tx];
#pragma unroll
        for (int jt = 0; jt < 4; jt++)
#pragma unroll
            for (int r = 0; r < 4; r++) {
                int j = b * 64 + jt * 16 + quad * 4 + r;
                acc2[jt][0][r] += rv0 + sendT[j * 128 + ob + tx];
                acc2[jt][1][r] += rv1 + sendT[j * 128 + ob + 16 + tx];
            }
    }

    // LN row partials (32 cols per wave) -> LDS
#pragma unroll
    for (int jt = 0; jt < 4; jt++) {
        float s4[4], q4[4];
#pragma unroll
        for (int r = 0; r < 4; r++) {
            float a0 = acc2[jt][0][r], a1 = acc2[jt][1][r];
            s4[r] = a0 + a1; q4[r] = a0 * a0 + a1 * a1;
        }
#pragma unroll
        for (int m = 1; m < 16; m <<= 1)
#pragma unroll
            for (int r = 0; r < 4; r++) {
                s4[r] += __shfl_xor(s4[r], m, 64);
                q4[r] += __shfl_xor(q4[r], m, 64);
            }
        if (tx == 0)
#pragma unroll
            for (int r = 0; r < 4; r++) {
                redS[w * 64 + jt * 16 + quad * 4 + r] = s4[r];
                redQ[w * 64 + jt * 16 + quad * 4 + r] = q4[r];
            }
    }
    __syncthreads();

    // normalize + relu + per-col agg
    {
        float lw0 = lnws[ob + tx], lb0 = lnbs[ob + tx];
        float lw1 = lnws[ob + 16 + tx], lb1 = lnbs[ob + 16 + tx];
        float ag0 = 0.f, ag1 = 0.f;
#pragma unroll
        for (int jt = 0; jt < 4; jt++)
#pragma unroll
            for (int r = 0; r < 4; r++) {
                int row = jt * 16 + quad * 4 + r;
                float ss = redS[row] + redS[64 + row] + redS[128 + row] + redS[192 + row];
                float qq = redQ[row] + redQ[64 + row] + redQ[128 + row] + redQ[192 + row];
                float mu = ss * (1.f / 128.f);
                float rsd = rsqrtf(qq * (1.f / 128.f) - mu * mu + 1e-5f);
                float z0 = (acc2[jt][0][r] - mu) * rsd * lw0 + lb0;
                float z1 = (acc2[jt][1][r] - mu) * rsd * lw1 + lb1;
                ag0 += fmaxf(z0, 0.f);
                ag1 += fmaxf(z1, 0.f);
            }
        ag0 += __shfl_xor(ag0, 16, 64); ag0 += __shfl_xor(ag0, 32, 64);
        ag1 += __shfl_xor(ag1, 16, 64); ag1 += __shfl_xor(ag1, 32, 64);
        if (quad == 0) {
            aggb[blkg * 128 + ob + tx]      = f2b(ag0);
            aggb[blkg * 128 + ob + 16 + tx] = f2b(ag1);
        }
    }
}

// ---------------- k_prop_edge2: step-1, no GEMM (unchanged) ----------------
__global__ __launch_bounds__(256)
void k_prop_edge2(const u16* __restrict__ Ebuf,
                  const float* __restrict__ rp_lnw, const float* __restrict__ rp_lnb,
                  const float* __restrict__ recvT, const float* __restrict__ sendT,
                  u16* __restrict__ aggb)
{
    const int blk = blockIdx.x;   // b*64 + i
    const int b = blk >> 6;
    const int t = threadIdx.x;
    __shared__ float scr[16 * 132];
    __shared__ float lnws[128], lnbs[128];
    if (t < 128) { lnws[t] = rp_lnw[t]; lnbs[t] = rp_lnb[t]; }
    __syncthreads();

    const int wave = t >> 6, lane = t & 63, tx = lane & 15, quad = lane >> 4;
    const int tid = blk * 4 + wave;
    const int jrow = wave * 16 + quad * 4;

    float y[8][4];
#pragma unroll
    for (int oo = 0; oo < 8; oo++) {
        bf16x4 v = *(const bf16x4*)(Ebuf + ((size_t)(tid * 8 + oo) * 64 + lane) * 4);
        const int o = oo * 16 + tx;
        float rv = recvT[blk * 128 + o];
#pragma unroll
        for (int r = 0; r < 4; r++)
            y[oo][r] = bsu((u16)v[r]) + rv + sendT[(b * 64 + jrow + r) * 128 + o];
    }
    float s[4], q[4];
#pragma unroll
    for (int r = 0; r < 4; r++) {
        s[r] = 0.f; q[r] = 0.f;
#pragma unroll
        for (int oo = 0; oo < 8; oo++) { s[r] += y[oo][r]; q[r] += y[oo][r] * y[oo][r]; }
    }
#pragma unroll
    for (int m = 1; m < 16; m <<= 1) {
#pragma unroll
        for (int r = 0; r < 4; r++) {
            s[r] += __shfl_xor(s[r], m, 64);
            q[r] += __shfl_xor(q[r], m, 64);
        }
    }
    float mu[4], rs[4];
#pragma unroll
    for (int r = 0; r < 4; r++) {
        mu[r] = s[r] * (1.f / 128.f);
        rs[r] = rsqrtf(q[r] * (1.f / 128.f) - mu[r] * mu[r] + 1e-5f);
    }
    float pa[8];
#pragma unroll
    for (int oo = 0; oo < 8; oo++) {
        const int o = oo * 16 + tx;
        float lw = lnws[o], lb = lnbs[o];
        float p = 0.f;
#pragma unroll
        for (int r = 0; r < 4; r++) {
            float z = (y[oo][r] - mu[r]) * rs[r] * lw + lb;
            p += fmaxf(z, 0.f);
        }
        pa[oo] = p;
    }
    const int grp = wave * 4 + quad;
#pragma unroll
    for (int oo = 0; oo < 8; oo++) scr[grp * 132 + oo * 16 + tx] = pa[oo];
    __syncthreads();
    if (t < 128) {
        float sum = 0.f;
#pragma unroll
        for (int gg = 0; gg < 16; gg++) sum += scr[gg * 132 + t];
        aggb[blk * 128 + t] = f2b(sum);
    }
}

// ---------------- k_prop_node: 16 rows/block MFMA (unchanged) ----------------
__global__ __launch_bounds__(256)
void k_prop_node(const u16* __restrict__ aggb,
                 const u16* __restrict__ pp_wb, const float* __restrict__ pp_b,
                 const float* __restrict__ pp_lnw, const float* __restrict__ pp_lnb,
                 const u16* __restrict__ wrecvb, const u16* __restrict__ wsendb,
                 const float* __restrict__ rp_b,
                 u16* __restrict__ objb, float* __restrict__ recvT, float* __restrict__ sendT,
                 int compute_terms)
{
    const int r0 = blockIdx.x * 16;
    const int t = threadIdx.x;
    __shared__ __align__(16) u16 ab[16 * 264];
    __shared__ __align__(16) u16 ob[16 * 136];
    __shared__ float redS[64], redQ[64];

    for (int i = t; i < 512; i += 256) {
        int m = i >> 5, c = i & 31;
        uint4 v = (c < 16) ? *(const uint4*)&objb[(r0 + m) * 128 + (c & 15) * 8]
                           : *(const uint4*)&aggb[(r0 + m) * 128 + (c - 16) * 8];
        *(uint4*)&ab[m * 264 + c * 8] = v;
    }
    __syncthreads();

    const int wave = t >> 6, lane = t & 63, tx = lane & 15, quad = lane >> 4;
    bf16x8 afr[8];
#pragma unroll
    for (int kk = 0; kk < 8; kk++) afr[kk] = *(const bf16x8*)&ab[tx * 264 + kk * 32 + quad * 8];
    f32x4 acc[2]; acc[0] = (f32x4){0.f,0.f,0.f,0.f}; acc[1] = acc[0];
#pragma unroll
    for (int ot = 0; ot < 2; ot++) {
        int o = (wave * 2 + ot) * 16 + tx;
#pragma unroll
        for (int kk = 0; kk < 8; kk++) {
            bf16x8 bfr = *(const bf16x8*)&pp_wb[o * 256 + kk * 32 + quad * 8];
            acc[ot] = __builtin_amdgcn_mfma_f32_16x16x32_bf16(afr[kk], bfr, acc[ot], 0, 0, 0);
        }
    }
#pragma unroll
    for (int ot = 0; ot < 2; ot++) {
        float bia = pp_b[(wave * 2 + ot) * 16 + tx];
#pragma unroll
        for (int r = 0; r < 4; r++) acc[ot][r] += bia;
    }

    float s[4], q[4];
#pragma unroll
    for (int r = 0; r < 4; r++) {
        s[r] = acc[0][r] + acc[1][r];
        q[r] = acc[0][r] * acc[0][r] + acc[1][r] * acc[1][r];
    }
#pragma unroll
    for (int m = 1; m < 16; m <<= 1) {
#pragma unroll
        for (int r = 0; r < 4; r++) {
            s[r] += __shfl_xor(s[r], m, 64);
            q[r] += __shfl_xor(q[r], m, 64);
        }
    }
    if (tx == 0) {
#pragma unroll
        for (int r = 0; r < 4; r++) {
            redS[wave * 16 + quad * 4 + r] = s[r];
            redQ[wave * 16 + quad * 4 + r] = q[r];
        }
    }
    __syncthreads();
    float mu[4], rs[4];
#pragma unroll
    for (int r = 0; r < 4; r++) {
        int m = quad * 4 + r;
        float ss = redS[m] + redS[16 + m] + redS[32 + m] + redS[48 + m];
        float qq = redQ[m] + redQ[16 + m] + redQ[32 + m] + redQ[48 + m];
        mu[r] = ss * (1.f / 128.f);
        rs[r] = rsqrtf(qq * (1.f / 128.f) - mu[r] * mu[r] + 1e-5f);
    }
#pragma unroll
    for (int ot = 0; ot < 2; ot++) {
        int o = (wave * 2 + ot) * 16 + tx;
        float lw = pp_lnw[o], lb = pp_lnb[o];
#pragma unroll
        for (int r = 0; r < 4; r++) {
            float z = (acc[ot][r] - mu[r]) * rs[r] * lw + lb;
            ob[(quad * 4 + r) * 136 + o] = f2b(fmaxf(z, 0.f));
        }
    }
    __syncthreads();
    { int m = t >> 4, c = t & 15;
      *(uint4*)&objb[(r0 + m) * 128 + c * 8] = *(const uint4*)&ob[m * 136 + c * 8]; }

    if (compute_terms) {
        bf16x8 af2[4];
#pragma unroll
        for (int kk = 0; kk < 4; kk++) af2[kk] = *(const bf16x8*)&ob[tx * 136 + kk * 32 + quad * 8];
        f32x4 ar[2], an[2];
        ar[0] = (f32x4){0.f,0.f,0.f,0.f}; ar[1] = ar[0]; an[0] = ar[0]; an[1] = ar[0];
#pragma unroll
        for (int ot = 0; ot < 2; ot++) {
            int o = (wave * 2 + ot) * 16 + tx;
#pragma unroll
            for (int kk = 0; kk < 4; kk++) {
                bf16x8 br = *(const bf16x8*)&wrecvb[o * 128 + kk * 32 + quad * 8];
                ar[ot] = __builtin_amdgcn_mfma_f32_16x16x32_bf16(af2[kk], br, ar[ot], 0, 0, 0);
                bf16x8 bs = *(const bf16x8*)&wsendb[o * 128 + kk * 32 + quad * 8];
                an[ot] = __builtin_amdgcn_mfma_f32_16x16x32_bf16(af2[kk], bs, an[ot], 0, 0, 0);
            }
        }
#pragma unroll
        for (int ot = 0; ot < 2; ot++) {
            int o = (wave * 2 + ot) * 16 + tx;
            float rb = rp_b[o];
#pragma unroll
            for (int r = 0; r < 4; r++) {
                recvT[(r0 + quad * 4 + r) * 128 + o] = ar[ot][r] + rb;
                sendT[(r0 + quad * 4 + r) * 128 + o] = an[ot][r];
            }
        }
    }
}

// ---------------- k_predict: 16 rows/block MFMA (unchanged) ----------------
__global__ __launch_bounds__(256)
void k_predict(const u16* __restrict__ objb,
               const u16* __restrict__ pr_w0b, const float* __restrict__ pr_b0,
               const u16* __restrict__ pr_w1b, const float* __restrict__ pr_b1,
               float* __restrict__ out)
{
    const int r0 = blockIdx.x * 16;
    const int t = threadIdx.x;
    __shared__ __align__(16) u16 ab[16 * 136];
    __shared__ __align__(16) u16 hb2[16 * 136];
    { int m = t >> 4, c = t & 15;
      *(uint4*)&ab[m * 136 + c * 8] = *(const uint4*)&objb[(r0 + m) * 128 + c * 8]; }
    __syncthreads();

    const int wave = t >> 6, lane = t & 63, tx = lane & 15, quad = lane >> 4;
    bf16x8 afr[4];
#pragma unroll
    for (int kk = 0; kk < 4; kk++) afr[kk] = *(const bf16x8*)&ab[tx * 136 + kk * 32 + quad * 8];
    f32x4 acc[2]; acc[0] = (f32x4){0.f,0.f,0.f,0.f}; acc[1] = acc[0];
#pragma unroll
    for (int ot = 0; ot < 2; ot++) {
        int o = (wave * 2 + ot) * 16 + tx;
#pragma unroll
        for (int kk = 0; kk < 4; kk++) {
            bf16x8 bfr = *(const bf16x8*)&pr_w0b[o * 128 + kk * 32 + quad * 8];
            acc[ot] = __builtin_amdgcn_mfma_f32_16x16x32_bf16(afr[kk], bfr, acc[ot], 0, 0, 0);
        }
    }
#pragma unroll
    for (int ot = 0; ot < 2; ot++) {
        int o = (wave * 2 + ot) * 16 + tx;
        float bia = pr_b0[o];
#pragma unroll
        for (int r = 0; r < 4; r++)
            hb2[(quad * 4 + r) * 136 + o] = f2b(fmaxf(acc[ot][r] + bia, 0.f));
    }
    __syncthreads();
    if (wave < 2) {
        bf16x8 af2[4];
#pragma unroll
        for (int kk = 0; kk < 4; kk++) af2[kk] = *(const bf16x8*)&hb2[tx * 136 + kk * 32 + quad * 8];
        f32x4 a2 = (f32x4){0.f,0.f,0.f,0.f};
        int o = wave * 16 + tx;
#pragma unroll
        for (int kk = 0; kk < 4; kk++) {
            bf16x8 bfr = *(const bf16x8*)&pr_w1b[o * 128 + kk * 32 + quad * 8];
            a2 = __builtin_amdgcn_mfma_f32_16x16x32_bf16(af2[kk], bfr, a2, 0, 0, 0);
        }
        float bia = pr_b1[o];
#pragma unroll
        for (int r = 0; r < 4; r++)
            out[(r0 + quad * 4 + r) * 32 + o] = tanhf(a2[r] + bia);
    }
}

extern "C" void kernel_launch(void* const* d_in, const int* in_sizes, int n_in,
                              void* d_out, int out_size, void* d_ws, size_t ws_size,
                              hipStream_t stream)
{
    const float* attrs    = (const float*)d_in[0];
    const float* states   = (const float*)d_in[1];
    const float* rel_attrs= (const float*)d_in[3];
    const float* oe_w0 = (const float*)d_in[4];
    const float* oe_b0 = (const float*)d_in[5];
    const float* oe_w1 = (const float*)d_in[6];
    const float* oe_b1 = (const float*)d_in[7];
    const float* re_w0 = (const float*)d_in[8];
    const float* re_b0 = (const float*)d_in[9];
    const float* re_w1 = (const float*)d_in[10];
    const float* re_b1 = (const float*)d_in[11];
    const float* rp_w  = (const float*)d_in[12];
    const float* rp_b  = (const float*)d_in[13];
    const float* rp_lnw= (const float*)d_in[14];
    const float* rp_lnb= (const float*)d_in[15];
    const float* pp_w  = (const float*)d_in[16];
    const float* pp_b  = (const float*)d_in[17];
    const float* pp_lnw= (const float*)d_in[18];
    const float* pp_lnb= (const float*)d_in[19];
    const float* pr_w0 = (const float*)d_in[20];
    const float* pr_b0 = (const float*)d_in[21];
    const float* pr_w1 = (const float*)d_in[22];
    const float* pr_b1 = (const float*)d_in[23];
    // d_in[24] = pstep (always 2)

    float* ws    = (float*)d_ws;
    float* nr    = ws;
    float* ns    = nr    + ROWS * 128;
    float* recvT = ns    + ROWS * 128;
    float* sendT = recvT + ROWS * 128;
    u16* re_w1b = (u16*)(sendT + ROWS * 128);
    u16* web    = re_w1b + 16384;
    u16* oe_w1b = web    + 16384;
    u16* wrecvb = oe_w1b + 16384;
    u16* wsendb = wrecvb + 16384;
    u16* pp_wb  = wsendb + 16384;
    u16* pr_w0b = pp_wb  + 32768;
    u16* pr_w1b = pr_w0b + 16384;
    u16* objb   = pr_w1b + 4096;
    u16* aggb   = objb + ROWS * 128;
    u16* Ebuf   = aggb + ROWS * 128;   // 8192 tiles * 8 * 64 * 4 bf16 (33.5 MB)

    k_prep<<<528, 256, 0, stream>>>(re_w1, rp_w, oe_w1, pp_w, pr_w0, pr_w1,
                                    re_w1b, web, oe_w1b, wrecvb, wsendb,
                                    pp_wb, pr_w0b, pr_w1b);
    k_node<<<128, 256, 0, stream>>>(attrs, states, oe_w0, oe_b0, oe_w1b, oe_b1,
                                    re_w0, re_b0, wrecvb, wsendb, rp_b,
                                    objb, nr, ns, recvT, sendT);
    k_edge_fused<<<2048, 256, 0, stream>>>(rel_attrs, re_w0, re_w1b, web, re_b1,
                                           rp_lnw, rp_lnb, nr, ns, recvT, sendT,
                                           Ebuf, aggb);
    k_prop_node<<<128, 256, 0, stream>>>(aggb, pp_wb, pp_b, pp_lnw, pp_lnb,
                                         wrecvb, wsendb, rp_b,
                                         objb, recvT, sendT, 1);
    k_prop_edge2<<<2048, 256, 0, stream>>>(Ebuf, rp_lnw, rp_lnb, recvT, sendT, aggb);
    k_prop_node<<<128, 256, 0, stream>>>(aggb, pp_wb, pp_b, pp_lnw, pp_lnb,
                                         wrecvb, wsendb, rp_b,
                                         objb, recvT, sendT, 0);
    k_predict<<<128, 256, 0, stream>>>(objb, pr_w0b, pr_b0, pr_w1b, pr_b1, (float*)d_out);
}